// Round 3
// baseline (452.276 us; speedup 1.0000x reference)
//
#include <hip/hip_runtime.h>

// SpikeLatencyLIFEncoder, two-phase:
//  1) lif_compute_ts: per element run the fp32 LIF recurrence (exact-match
//     _rn intrinsics, no FMA contraction), record first-spike step as u8
//     into d_ws (1 MB).
//  2) lif_store_spikes: pure streaming-store kernel, grid (n4/256, 100),
//     blockIdx.y = t so the concurrent write front is contiguous per
//     time-slab. Nontemporal float4 stores (output never re-read).
// Output [100, 256, 4096] f32 = 419 MB -> HBM-write-bound, roofline ~67 us.

#define SEQ_LEN 100

// Native vector type: __builtin_nontemporal_store rejects HIP_vector_type.
typedef float nfloat4 __attribute__((ext_vector_type(4)));

__global__ __launch_bounds__(256) void lif_compute_ts(
    const float4* __restrict__ in, uchar4* __restrict__ ts_out, int n4) {
    int i = blockIdx.x * blockDim.x + threadIdx.x;
    if (i >= n4) return;

    float4 I4 = in[i];
    float Iv[4] = {I4.x, I4.y, I4.z, I4.w};
    unsigned char ts[4];

    #pragma unroll
    for (int c = 0; c < 4; ++c) {
        float Ic = Iv[c];
        float v = 0.0f;
        int t = 0;
        for (; t < SEQ_LEN; ++t) {
            // v = v + 0.1f * ((0.0f - v) + I)  -- exact fp32, no FMA
            float d = __fadd_rn(__fsub_rn(0.0f, v), Ic);
            v = __fadd_rn(v, __fmul_rn(0.1f, d));
            if (v > 1.0f) break;  // == (v - 1.0f) > 0.0f in fp32
        }
        ts[c] = (unsigned char)t;  // SEQ_LEN (100) == never spikes
    }
    ts_out[i] = make_uchar4(ts[0], ts[1], ts[2], ts[3]);
}

__global__ __launch_bounds__(256) void lif_store_spikes(
    const uchar4* __restrict__ ts_in, nfloat4* __restrict__ out, int n4) {
    int i = blockIdx.x * blockDim.x + threadIdx.x;  // float4 index within slab
    int t = blockIdx.y;                             // time step
    uchar4 ts = ts_in[i];                           // 4 B/lane, L2-cached re-read

    nfloat4 val;
    val.x = (ts.x == (unsigned char)t) ? 1.0f : 0.0f;
    val.y = (ts.y == (unsigned char)t) ? 1.0f : 0.0f;
    val.z = (ts.z == (unsigned char)t) ? 1.0f : 0.0f;
    val.w = (ts.w == (unsigned char)t) ? 1.0f : 0.0f;

    __builtin_nontemporal_store(val, &out[(size_t)t * n4 + i]);
}

extern "C" void kernel_launch(void* const* d_in, const int* in_sizes, int n_in,
                              void* d_out, int out_size, void* d_ws, size_t ws_size,
                              hipStream_t stream) {
    const float* in = (const float*)d_in[0];
    int n = in_sizes[0];   // 256*4096 = 1,048,576 (multiple of 1024)
    int n4 = n / 4;        // 262,144 float4 elements per time slab

    uchar4* ts_buf = (uchar4*)d_ws;  // n4 uchar4 = 1 MB, well within ws

    int threads = 256;
    int blocks_x = (n4 + threads - 1) / threads;  // 1024

    lif_compute_ts<<<blocks_x, threads, 0, stream>>>(
        (const float4*)in, ts_buf, n4);

    dim3 grid(blocks_x, SEQ_LEN);  // (1024, 100)
    lif_store_spikes<<<grid, threads, 0, stream>>>(
        (const uchar4*)ts_buf, (nfloat4*)d_out, n4);
}